// Round 1
// baseline (316.810 us; speedup 1.0000x reference)
//
#include <hip/hip_runtime.h>

// Radix-select (exact k-th order statistic) + mask, fp32, n = 64*1024*1024.
//
// ws layout (unsigned):
//   [0..15]  state: [0]=b1 [1]=r2 [2]=b2 [3]=r3 [4]=b3 [5]=scratch [7]=thr bits
//   [16..]           hist1[4096], hist2[4096], hist3[256]
#define HIST1_OFF 16
#define HIST2_OFF (16 + 4096)
#define HIST3_OFF (16 + 8192)
#define WS_INTS   (16 + 4096 + 4096 + 256)

__device__ __forceinline__ unsigned map_bits(unsigned raw) {
    // monotone float->uint mapping (ascending order)
    return (raw & 0x80000000u) ? ~raw : (raw | 0x80000000u);
}

__global__ void __launch_bounds__(256)
hist_pass(const uint4* __restrict__ x, int n4, int shift, int nbins, int mode,
          const unsigned* __restrict__ state, unsigned* __restrict__ hist)
{
    __shared__ unsigned lh[4096];
    for (int i = threadIdx.x; i < nbins; i += blockDim.x) lh[i] = 0u;
    __syncthreads();

    unsigned tgt = 0; int mshift = 0;
    if (mode == 1)      { tgt = state[0];                      mshift = 20; }
    else if (mode == 2) { tgt = (state[0] << 12) | state[2];   mshift = 8;  }

    const unsigned binmask = (unsigned)(nbins - 1);
    int idx = blockIdx.x * blockDim.x + threadIdx.x;
    int stride = gridDim.x * blockDim.x;
    for (int i = idx; i < n4; i += stride) {
        uint4 v = x[i];
        unsigned u;
        u = map_bits(v.x); if (!mode || (u >> mshift) == tgt) atomicAdd(&lh[(u >> shift) & binmask], 1u);
        u = map_bits(v.y); if (!mode || (u >> mshift) == tgt) atomicAdd(&lh[(u >> shift) & binmask], 1u);
        u = map_bits(v.z); if (!mode || (u >> mshift) == tgt) atomicAdd(&lh[(u >> shift) & binmask], 1u);
        u = map_bits(v.w); if (!mode || (u >> mshift) == tgt) atomicAdd(&lh[(u >> shift) & binmask], 1u);
    }
    __syncthreads();
    for (int i = threadIdx.x; i < nbins; i += blockDim.x) {
        unsigned c = lh[i];
        if (c) atomicAdd(&hist[i], c);
    }
}

// Single block of 1024 threads: find bin containing `rank`, output bin and residual rank.
__global__ void __launch_bounds__(1024)
scan_select(const unsigned* __restrict__ hist, int nbins,
            const unsigned* __restrict__ rank_in, unsigned rank_imm,
            unsigned* __restrict__ bin_out, unsigned* __restrict__ rank_out)
{
    __shared__ unsigned s[1024];
    int t = threadIdx.x;
    unsigned rank = rank_in ? *rank_in : rank_imm;
    int per = (nbins + 1023) >> 10;
    int base = t * per;
    unsigned mySum = 0;
    for (int i = 0; i < per; ++i) {
        int b = base + i;
        if (b < nbins) mySum += hist[b];
    }
    s[t] = mySum;
    __syncthreads();
    // Hillis-Steele inclusive scan
    for (int off = 1; off < 1024; off <<= 1) {
        unsigned v = (t >= off) ? s[t - off] : 0u;
        __syncthreads();
        s[t] += v;
        __syncthreads();
    }
    unsigned incl = s[t];
    unsigned excl = incl - mySum;
    if (rank >= excl && rank < incl) {   // exactly one owner (half-open disjoint ranges)
        unsigned run = excl;
        for (int i = 0; i < per; ++i) {
            int b = base + i;
            unsigned c = (b < nbins) ? hist[b] : 0u;
            if (rank < run + c) { *bin_out = (unsigned)b; *rank_out = rank - run; break; }
            run += c;
        }
    }
}

__global__ void finalize_thr(unsigned* state) {
    unsigned u = (state[0] << 20) | (state[2] << 8) | state[4];
    // inverse of map_bits
    state[7] = (u & 0x80000000u) ? (u & 0x7FFFFFFFu) : ~u;
}

__global__ void __launch_bounds__(256)
mask_kernel(const float4* __restrict__ x, float4* __restrict__ out, int n4,
            const unsigned* __restrict__ state)
{
    float thr = __uint_as_float(state[7]);
    int idx = blockIdx.x * blockDim.x + threadIdx.x;
    int stride = gridDim.x * blockDim.x;
    for (int i = idx; i < n4; i += stride) {
        float4 v = x[i];
        float4 o;
        o.x = (v.x >= thr) ? 1.0f : 0.0f;
        o.y = (v.y >= thr) ? 1.0f : 0.0f;
        o.z = (v.z >= thr) ? 1.0f : 0.0f;
        o.w = (v.w >= thr) ? 1.0f : 0.0f;
        out[i] = o;
    }
}

extern "C" void kernel_launch(void* const* d_in, const int* in_sizes, int n_in,
                              void* d_out, int out_size, void* d_ws, size_t ws_size,
                              hipStream_t stream)
{
    const float* x = (const float*)d_in[0];
    float* out = (float*)d_out;
    long long n = (long long)in_sizes[0];
    long long k = (long long)((double)n * 0.9);   // matches Python int(n * RATIO)

    if (k <= 0) {
        hipMemsetAsync(d_out, 0, (size_t)out_size * sizeof(float), stream);
        return;
    }

    unsigned* ws = (unsigned*)d_ws;
    unsigned* st = ws;
    unsigned* h1 = ws + HIST1_OFF;
    unsigned* h2 = ws + HIST2_OFF;
    unsigned* h3 = ws + HIST3_OFF;

    int n4 = (int)(n / 4);                         // n is a multiple of 4
    const uint4* x4 = (const uint4*)x;
    unsigned r = (unsigned)(n - k);                // 0-indexed ascending rank of threshold

    hipMemsetAsync(d_ws, 0, WS_INTS * sizeof(unsigned), stream);

    hist_pass<<<2048, 256, 0, stream>>>(x4, n4, 20, 4096, 0, st, h1);
    scan_select<<<1, 1024, 0, stream>>>(h1, 4096, nullptr, r, &st[0], &st[1]);
    hist_pass<<<2048, 256, 0, stream>>>(x4, n4, 8, 4096, 1, st, h2);
    scan_select<<<1, 1024, 0, stream>>>(h2, 4096, &st[1], 0u, &st[2], &st[3]);
    hist_pass<<<2048, 256, 0, stream>>>(x4, n4, 0, 256, 2, st, h3);
    scan_select<<<1, 1024, 0, stream>>>(h3, 256, &st[3], 0u, &st[4], &st[5]);
    finalize_thr<<<1, 1, 0, stream>>>(st);
    mask_kernel<<<2048, 256, 0, stream>>>((const float4*)x, (float4*)out, n4, st);
}

// Round 2
// 247.603 us; speedup vs baseline: 1.2795x; 1.2795x over previous
//
#include <hip/hip_runtime.h>

// Exact k-th order statistic (radix-select) + mask, fp32, n = 64*1024*1024.
//
// Fast path (needs ~36.2 MB ws):
//   p1: 12-bit LDS hist -> scan -> (b1, r2)
//   p2: fused mask-write + 20-bit global hist + candidate compaction for bin b1
//   scan chain over 1M bins -> exact threshold bits
//   fixup: scatter-write 1.0f for candidates >= thr
// Fallback (small ws): proven 3-pass radix + mask.
//
// ws int layout (fast path):
//   [0..15]   state: [0]=b1 [1]=r2 [2]=chunk [3]=r2' [4]=b2lo [5]=res
//             [7]=thr (mapped u fast / float-bits fallback) [8]=cand_count
//   H1   [16 .. +4096)        12-bit hist
//   PART [.. +1024)           chunk partial sums
//   H20  [.. +1048576)        20-bit refine hist
//   CAND [..]                 uint2 (u, idx) candidate pairs

#define ST_OFF    0
#define H1_OFF    16
#define PART_OFF  (16 + 4096)
#define H20_OFF   (16 + 4096 + 1024)
#define CAND_OFF  (16 + 4096 + 1024 + 1048576)
#define FIXED_INTS CAND_OFF
#define CAND_CAP  (4u * 1024u * 1024u)

// fallback layout (old)
#define FB_H1_OFF 16
#define FB_H2_OFF (16 + 4096)
#define FB_H3_OFF (16 + 8192)
#define FB_WS_INTS (16 + 4096 + 4096 + 256)

__device__ __forceinline__ unsigned map_bits(unsigned raw) {
    return (raw & 0x80000000u) ? ~raw : (raw | 0x80000000u);
}

__global__ void __launch_bounds__(256)
hist_pass(const uint4* __restrict__ x, int n4, int shift, int nbins, int mode,
          const unsigned* __restrict__ state, unsigned* __restrict__ hist)
{
    __shared__ unsigned lh[4096];
    for (int i = threadIdx.x; i < nbins; i += blockDim.x) lh[i] = 0u;
    __syncthreads();

    unsigned tgt = 0; int mshift = 0;
    if (mode == 1)      { tgt = state[0];                      mshift = 20; }
    else if (mode == 2) { tgt = (state[0] << 12) | state[2];   mshift = 8;  }

    const unsigned binmask = (unsigned)(nbins - 1);
    int idx = blockIdx.x * blockDim.x + threadIdx.x;
    int stride = gridDim.x * blockDim.x;
    for (int i = idx; i < n4; i += stride) {
        uint4 v = x[i];
        unsigned u;
        u = map_bits(v.x); if (!mode || (u >> mshift) == tgt) atomicAdd(&lh[(u >> shift) & binmask], 1u);
        u = map_bits(v.y); if (!mode || (u >> mshift) == tgt) atomicAdd(&lh[(u >> shift) & binmask], 1u);
        u = map_bits(v.z); if (!mode || (u >> mshift) == tgt) atomicAdd(&lh[(u >> shift) & binmask], 1u);
        u = map_bits(v.w); if (!mode || (u >> mshift) == tgt) atomicAdd(&lh[(u >> shift) & binmask], 1u);
    }
    __syncthreads();
    for (int i = threadIdx.x; i < nbins; i += blockDim.x) {
        unsigned c = lh[i];
        if (c) atomicAdd(&hist[i], c);
    }
}

// One block, 1024 threads. hist_eff = hist + (*chunk_sel)*chunk_mul if chunk_sel.
__global__ void __launch_bounds__(1024)
scan_select(const unsigned* __restrict__ hist, int nbins,
            const unsigned* __restrict__ chunk_sel, int chunk_mul,
            const unsigned* __restrict__ rank_in, unsigned rank_imm,
            unsigned* __restrict__ bin_out, unsigned* __restrict__ rank_out)
{
    __shared__ unsigned s[1024];
    int t = threadIdx.x;
    const unsigned* h = hist + (chunk_sel ? (size_t)(*chunk_sel) * (size_t)chunk_mul : 0);
    unsigned rank = rank_in ? *rank_in : rank_imm;
    int per = (nbins + 1023) >> 10;
    int base = t * per;
    unsigned mySum = 0;
    for (int i = 0; i < per; ++i) {
        int b = base + i;
        if (b < nbins) mySum += h[b];
    }
    s[t] = mySum;
    __syncthreads();
    for (int off = 1; off < 1024; off <<= 1) {
        unsigned v = (t >= off) ? s[t - off] : 0u;
        __syncthreads();
        s[t] += v;
        __syncthreads();
    }
    unsigned incl = s[t];
    unsigned excl = incl - mySum;
    if (rank >= excl && rank < incl) {
        unsigned run = excl;
        for (int i = 0; i < per; ++i) {
            int b = base + i;
            unsigned c = (b < nbins) ? h[b] : 0u;
            if (rank < run + c) { *bin_out = (unsigned)b; *rank_out = rank - run; break; }
            run += c;
        }
    }
}

// ---------- fast path kernels ----------

__global__ void __launch_bounds__(256)
pass2_fused(const uint4* __restrict__ x, int n4, float4* __restrict__ out,
            unsigned* __restrict__ h20, uint2* __restrict__ cand, unsigned cap,
            unsigned* __restrict__ state)
{
    __shared__ uint2 lbuf[2048];
    __shared__ unsigned lcnt;
    __shared__ unsigned lbase;
    if (threadIdx.x == 0) lcnt = 0u;
    __syncthreads();

    const unsigned b1 = state[0];
    int idx = blockIdx.x * blockDim.x + threadIdx.x;
    int stride = gridDim.x * blockDim.x;
    for (int i = idx; i < n4; i += stride) {
        uint4 v = x[i];
        float4 o;
        unsigned ebase = (unsigned)i * 4u;
        #pragma unroll
        for (int c = 0; c < 4; ++c) {
            unsigned raw = (c == 0) ? v.x : (c == 1) ? v.y : (c == 2) ? v.z : v.w;
            unsigned u = map_bits(raw);
            unsigned p = u >> 20;
            float oc = 0.0f;
            if (p > b1) {
                oc = 1.0f;
            } else if (p == b1) {
                atomicAdd(&h20[u & 0xFFFFFu], 1u);
                unsigned pos = atomicAdd(&lcnt, 1u);
                if (pos < 2048u) lbuf[pos] = make_uint2(u, ebase + (unsigned)c);
            }
            if (c == 0) o.x = oc; else if (c == 1) o.y = oc; else if (c == 2) o.z = oc; else o.w = oc;
        }
        out[i] = o;
    }
    __syncthreads();
    unsigned cnt = lcnt; if (cnt > 2048u) cnt = 2048u;
    if (threadIdx.x == 0) lbase = atomicAdd(&state[8], cnt);
    __syncthreads();
    unsigned gb = lbase;
    for (unsigned j = threadIdx.x; j < cnt; j += blockDim.x) {
        unsigned g = gb + j;
        if (g < cap) cand[g] = lbuf[j];
    }
}

__global__ void __launch_bounds__(256)
reduce_chunks(const unsigned* __restrict__ h20, unsigned* __restrict__ part)
{
    __shared__ unsigned s[256];
    unsigned sum = 0;
    int base = blockIdx.x * 1024;
    for (int t = threadIdx.x; t < 1024; t += 256) sum += h20[base + t];
    s[threadIdx.x] = sum;
    __syncthreads();
    for (int off = 128; off > 0; off >>= 1) {
        if (threadIdx.x < off) s[threadIdx.x] += s[threadIdx.x + off];
        __syncthreads();
    }
    if (threadIdx.x == 0) part[blockIdx.x] = s[0];
}

__global__ void finalize_fast(unsigned* state) {
    // mapped threshold bits: b1(12) | chunk(10) | binlo(10)
    state[7] = (state[0] << 20) | (state[2] << 10) | state[4];
}

__global__ void __launch_bounds__(256)
fixup(const uint2* __restrict__ cand, const unsigned* __restrict__ state,
      float* __restrict__ out, unsigned cap)
{
    unsigned thr = state[7];
    unsigned m = state[8]; if (m > cap) m = cap;
    unsigned idx = blockIdx.x * blockDim.x + threadIdx.x;
    unsigned stride = gridDim.x * blockDim.x;
    for (unsigned i = idx; i < m; i += stride) {
        uint2 cv = cand[i];
        if (cv.x >= thr) out[cv.y] = 1.0f;
    }
}

// ---------- fallback kernels ----------

__global__ void finalize_thr_fb(unsigned* state) {
    unsigned u = (state[0] << 20) | (state[2] << 8) | state[4];
    state[7] = (u & 0x80000000u) ? (u & 0x7FFFFFFFu) : ~u;
}

__global__ void __launch_bounds__(256)
mask_kernel(const float4* __restrict__ x, float4* __restrict__ out, int n4,
            const unsigned* __restrict__ state)
{
    float thr = __uint_as_float(state[7]);
    int idx = blockIdx.x * blockDim.x + threadIdx.x;
    int stride = gridDim.x * blockDim.x;
    for (int i = idx; i < n4; i += stride) {
        float4 v = x[i];
        float4 o;
        o.x = (v.x >= thr) ? 1.0f : 0.0f;
        o.y = (v.y >= thr) ? 1.0f : 0.0f;
        o.z = (v.z >= thr) ? 1.0f : 0.0f;
        o.w = (v.w >= thr) ? 1.0f : 0.0f;
        out[i] = o;
    }
}

extern "C" void kernel_launch(void* const* d_in, const int* in_sizes, int n_in,
                              void* d_out, int out_size, void* d_ws, size_t ws_size,
                              hipStream_t stream)
{
    const float* x = (const float*)d_in[0];
    float* out = (float*)d_out;
    long long n = (long long)in_sizes[0];
    long long k = (long long)((double)n * 0.9);   // matches Python int(n * RATIO)

    if (k <= 0) {
        hipMemsetAsync(d_out, 0, (size_t)out_size * sizeof(float), stream);
        return;
    }

    unsigned* ws = (unsigned*)d_ws;
    unsigned* st = ws + ST_OFF;
    int n4 = (int)(n / 4);
    const uint4* x4 = (const uint4*)x;
    unsigned r = (unsigned)(n - k);               // ascending rank of threshold

    size_t need_fast = (size_t)FIXED_INTS * 4 + (size_t)CAND_CAP * 8;

    if (ws_size >= need_fast) {
        unsigned* h1   = ws + H1_OFF;
        unsigned* part = ws + PART_OFF;
        unsigned* h20  = ws + H20_OFF;
        uint2*    cand = (uint2*)(ws + CAND_OFF);

        hipMemsetAsync(d_ws, 0, (size_t)FIXED_INTS * sizeof(unsigned), stream);

        hist_pass<<<2048, 256, 0, stream>>>(x4, n4, 20, 4096, 0, st, h1);
        scan_select<<<1, 1024, 0, stream>>>(h1, 4096, nullptr, 0, nullptr, r, &st[0], &st[1]);
        pass2_fused<<<2048, 256, 0, stream>>>(x4, n4, (float4*)out, h20, cand, CAND_CAP, st);
        reduce_chunks<<<1024, 256, 0, stream>>>(h20, part);
        scan_select<<<1, 1024, 0, stream>>>(part, 1024, nullptr, 0, &st[1], 0u, &st[2], &st[3]);
        scan_select<<<1, 1024, 0, stream>>>(h20, 1024, &st[2], 1024, &st[3], 0u, &st[4], &st[5]);
        finalize_fast<<<1, 1, 0, stream>>>(st);
        fixup<<<512, 256, 0, stream>>>(cand, st, out, CAND_CAP);
    } else {
        unsigned* h1 = ws + FB_H1_OFF;
        unsigned* h2 = ws + FB_H2_OFF;
        unsigned* h3 = ws + FB_H3_OFF;

        hipMemsetAsync(d_ws, 0, FB_WS_INTS * sizeof(unsigned), stream);

        hist_pass<<<2048, 256, 0, stream>>>(x4, n4, 20, 4096, 0, st, h1);
        scan_select<<<1, 1024, 0, stream>>>(h1, 4096, nullptr, 0, nullptr, r, &st[0], &st[1]);
        hist_pass<<<2048, 256, 0, stream>>>(x4, n4, 8, 4096, 1, st, h2);
        scan_select<<<1, 1024, 0, stream>>>(h2, 4096, nullptr, 0, &st[1], 0u, &st[2], &st[3]);
        hist_pass<<<2048, 256, 0, stream>>>(x4, n4, 0, 256, 2, st, h3);
        scan_select<<<1, 1024, 0, stream>>>(h3, 256, nullptr, 0, &st[3], 0u, &st[4], &st[5]);
        finalize_thr_fb<<<1, 1, 0, stream>>>(st);
        mask_kernel<<<2048, 256, 0, stream>>>((const float4*)x, (float4*)out, n4, st);
    }
}

// Round 3
// 245.602 us; speedup vs baseline: 1.2899x; 1.0081x over previous
//
#include <hip/hip_runtime.h>

// Exact k-th order statistic (radix-select) + mask, fp32, n = 64*1024*1024.
//
// Fast path (~139 MB ws):
//   p1: 12-bit LDS hist (fire-and-forget atomics) -> scan -> (b1, r2)
//   p2: fused mask-write + 20-bit global hist (no-return atomics) +
//       ATOMIC-FREE per-wave candidate compaction (ballot/popc prefix)
//   reduce_chunks + fused 2-level scan -> exact threshold bits
//   fixup: per-wave segments, scatter-write 1.0f for candidates >= thr
// Fallback (small ws): proven 3-pass radix + mask.

#define ST_OFF    0
#define H1_OFF    16
#define PART_OFF  (16 + 4096)
#define H20_OFF   (16 + 4096 + 1024)
#define FIXED_Z   (16 + 4096 + 1024 + 1048576)   // ints zeroed per call
#define CNT_OFF   FIXED_Z
#define NWAVES    8192                            // 2048 blocks * 256 thr / 64
#define CAND_OFF  (FIXED_Z + NWAVES)
#define SEG       2048u

// fallback layout
#define FB_H1_OFF 16
#define FB_H2_OFF (16 + 4096)
#define FB_H3_OFF (16 + 8192)
#define FB_WS_INTS (16 + 4096 + 4096 + 256)

__device__ __forceinline__ unsigned map_bits(unsigned raw) {
    return (raw & 0x80000000u) ? ~raw : (raw | 0x80000000u);
}

// ---------------- pass 1: 12-bit histogram ----------------

__global__ void __launch_bounds__(256)
hist12(const uint4* __restrict__ x, int n4, unsigned* __restrict__ hist)
{
    __shared__ unsigned lh[4096];
    for (int i = threadIdx.x; i < 4096; i += 256) lh[i] = 0u;
    __syncthreads();

    int idx = blockIdx.x * blockDim.x + threadIdx.x;
    int stride = gridDim.x * blockDim.x;
    for (int i = idx; i < n4; i += 2 * stride) {
        uint4 a = x[i];
        int j = i + stride;
        bool has2 = (j < n4);
        uint4 b;
        if (has2) b = x[j];
        atomicAdd(&lh[map_bits(a.x) >> 20], 1u);
        atomicAdd(&lh[map_bits(a.y) >> 20], 1u);
        atomicAdd(&lh[map_bits(a.z) >> 20], 1u);
        atomicAdd(&lh[map_bits(a.w) >> 20], 1u);
        if (has2) {
            atomicAdd(&lh[map_bits(b.x) >> 20], 1u);
            atomicAdd(&lh[map_bits(b.y) >> 20], 1u);
            atomicAdd(&lh[map_bits(b.z) >> 20], 1u);
            atomicAdd(&lh[map_bits(b.w) >> 20], 1u);
        }
    }
    __syncthreads();
    for (int i = threadIdx.x; i < 4096; i += 256) {
        unsigned c = lh[i];
        if (c) atomicAdd(&hist[i], c);
    }
}

// ---------------- generic single-block select (also used by fallback) ------

__global__ void __launch_bounds__(1024)
scan_select(const unsigned* __restrict__ hist, int nbins,
            const unsigned* __restrict__ chunk_sel, int chunk_mul,
            const unsigned* __restrict__ rank_in, unsigned rank_imm,
            unsigned* __restrict__ bin_out, unsigned* __restrict__ rank_out)
{
    __shared__ unsigned s[1024];
    int t = threadIdx.x;
    const unsigned* h = hist + (chunk_sel ? (size_t)(*chunk_sel) * (size_t)chunk_mul : 0);
    unsigned rank = rank_in ? *rank_in : rank_imm;
    int per = (nbins + 1023) >> 10;
    int base = t * per;
    unsigned mySum = 0;
    for (int i = 0; i < per; ++i) {
        int b = base + i;
        if (b < nbins) mySum += h[b];
    }
    s[t] = mySum;
    __syncthreads();
    for (int off = 1; off < 1024; off <<= 1) {
        unsigned v = (t >= off) ? s[t - off] : 0u;
        __syncthreads();
        s[t] += v;
        __syncthreads();
    }
    unsigned incl = s[t];
    unsigned excl = incl - mySum;
    if (rank >= excl && rank < incl) {
        unsigned run = excl;
        for (int i = 0; i < per; ++i) {
            int b = base + i;
            unsigned c = (b < nbins) ? h[b] : 0u;
            if (rank < run + c) { *bin_out = (unsigned)b; *rank_out = rank - run; break; }
            run += c;
        }
    }
}

// ---------------- pass 2: fused mask + refine hist + compaction ------------

__device__ __forceinline__ void cand_step(unsigned u, unsigned gi, unsigned b1,
                                          unsigned* __restrict__ h20,
                                          uint2* __restrict__ seg,
                                          unsigned& cnt, unsigned lane, float& oc)
{
    unsigned p = u >> 20;
    oc = (p > b1) ? 1.0f : 0.0f;
    bool c = (p == b1);
    if (c) atomicAdd(&h20[u & 0xFFFFFu], 1u);          // no return -> no wait
    unsigned long long m = __ballot(c);
    if (c) {
        unsigned pos = cnt + (unsigned)__popcll(m & ((1ull << lane) - 1ull));
        if (pos < SEG) seg[pos] = make_uint2(u, gi);
    }
    cnt += (unsigned)__popcll(m);                       // wave-uniform, SGPR
}

__global__ void __launch_bounds__(256)
pass2(const uint4* __restrict__ x, int n4, float4* __restrict__ out,
      unsigned* __restrict__ h20, uint2* __restrict__ cand,
      unsigned* __restrict__ cnt_out, const unsigned* __restrict__ state)
{
    const unsigned b1 = state[0];
    const unsigned lane = threadIdx.x & 63u;
    const unsigned wave = (unsigned)(blockIdx.x * blockDim.x + threadIdx.x) >> 6;
    uint2* seg = cand + (size_t)wave * SEG;
    unsigned cnt = 0;

    int idx = blockIdx.x * blockDim.x + threadIdx.x;
    int stride = gridDim.x * blockDim.x;
    for (int i = idx; i < n4; i += stride) {
        uint4 v = x[i];
        float4 o;
        unsigned gi = (unsigned)i * 4u;
        cand_step(map_bits(v.x), gi + 0u, b1, h20, seg, cnt, lane, o.x);
        cand_step(map_bits(v.y), gi + 1u, b1, h20, seg, cnt, lane, o.y);
        cand_step(map_bits(v.z), gi + 2u, b1, h20, seg, cnt, lane, o.z);
        cand_step(map_bits(v.w), gi + 3u, b1, h20, seg, cnt, lane, o.w);
        out[i] = o;
    }
    if (lane == 0) cnt_out[wave] = (cnt > SEG) ? SEG : cnt;
}

// ---------------- refine-hist reduction + fused 2-level scan ---------------

__global__ void __launch_bounds__(256)
reduce_chunks(const unsigned* __restrict__ h20, unsigned* __restrict__ part)
{
    __shared__ unsigned s[256];
    unsigned sum = 0;
    int base = blockIdx.x * 1024;
    for (int t = threadIdx.x; t < 1024; t += 256) sum += h20[base + t];
    s[threadIdx.x] = sum;
    __syncthreads();
    for (int off = 128; off > 0; off >>= 1) {
        if (threadIdx.x < off) s[threadIdx.x] += s[threadIdx.x + off];
        __syncthreads();
    }
    if (threadIdx.x == 0) part[blockIdx.x] = s[0];
}

// One block, 1024 threads: two chained 1024-bin selects, writes final thr bits.
__global__ void __launch_bounds__(1024)
scan20(const unsigned* __restrict__ h20, const unsigned* __restrict__ part,
       unsigned* __restrict__ state)
{
    __shared__ unsigned s[1024];
    __shared__ unsigned sh_bin, sh_res;
    int t = threadIdx.x;

    // level A: chunks
    unsigned rank = state[1];
    unsigned v = part[t];
    s[t] = v;
    __syncthreads();
    for (int off = 1; off < 1024; off <<= 1) {
        unsigned w = (t >= off) ? s[t - off] : 0u;
        __syncthreads();
        s[t] += w;
        __syncthreads();
    }
    {
        unsigned incl = s[t], excl = incl - v;
        if (rank >= excl && rank < incl) { sh_bin = (unsigned)t; sh_res = rank - excl; }
    }
    __syncthreads();
    unsigned chunk = sh_bin;
    unsigned r2 = sh_res;
    __syncthreads();

    // level B: bins within chunk
    v = h20[(size_t)chunk * 1024 + t];
    s[t] = v;
    __syncthreads();
    for (int off = 1; off < 1024; off <<= 1) {
        unsigned w = (t >= off) ? s[t - off] : 0u;
        __syncthreads();
        s[t] += w;
        __syncthreads();
    }
    {
        unsigned incl = s[t], excl = incl - v;
        if (r2 >= excl && r2 < incl) {
            state[7] = (state[0] << 20) | (chunk << 10) | (unsigned)t;  // mapped thr
        }
    }
}

// ---------------- fixup ----------------

__global__ void __launch_bounds__(256)
fixup(const uint2* __restrict__ cand, const unsigned* __restrict__ cnt,
      const unsigned* __restrict__ state, float* __restrict__ out, unsigned nwaves)
{
    unsigned thr = state[7];
    unsigned lane = threadIdx.x & 63u;
    unsigned wave = (unsigned)(blockIdx.x * blockDim.x + threadIdx.x) >> 6;
    if (wave >= nwaves) return;
    const uint2* seg = cand + (size_t)wave * SEG;
    unsigned m = cnt[wave];
    for (unsigned j = lane; j < m; j += 64u) {
        uint2 cv = seg[j];
        if (cv.x >= thr) out[cv.y] = 1.0f;
    }
}

// ---------------- fallback kernels (proven 3-pass) ----------------

__global__ void __launch_bounds__(256)
hist_pass(const uint4* __restrict__ x, int n4, int shift, int nbins, int mode,
          const unsigned* __restrict__ state, unsigned* __restrict__ hist)
{
    __shared__ unsigned lh[4096];
    for (int i = threadIdx.x; i < nbins; i += blockDim.x) lh[i] = 0u;
    __syncthreads();

    unsigned tgt = 0; int mshift = 0;
    if (mode == 1)      { tgt = state[0];                      mshift = 20; }
    else if (mode == 2) { tgt = (state[0] << 12) | state[2];   mshift = 8;  }

    const unsigned binmask = (unsigned)(nbins - 1);
    int idx = blockIdx.x * blockDim.x + threadIdx.x;
    int stride = gridDim.x * blockDim.x;
    for (int i = idx; i < n4; i += stride) {
        uint4 v = x[i];
        unsigned u;
        u = map_bits(v.x); if (!mode || (u >> mshift) == tgt) atomicAdd(&lh[(u >> shift) & binmask], 1u);
        u = map_bits(v.y); if (!mode || (u >> mshift) == tgt) atomicAdd(&lh[(u >> shift) & binmask], 1u);
        u = map_bits(v.z); if (!mode || (u >> mshift) == tgt) atomicAdd(&lh[(u >> shift) & binmask], 1u);
        u = map_bits(v.w); if (!mode || (u >> mshift) == tgt) atomicAdd(&lh[(u >> shift) & binmask], 1u);
    }
    __syncthreads();
    for (int i = threadIdx.x; i < nbins; i += blockDim.x) {
        unsigned c = lh[i];
        if (c) atomicAdd(&hist[i], c);
    }
}

__global__ void finalize_thr_fb(unsigned* state) {
    unsigned u = (state[0] << 20) | (state[2] << 8) | state[4];
    state[7] = (u & 0x80000000u) ? (u & 0x7FFFFFFFu) : ~u;
}

__global__ void __launch_bounds__(256)
mask_kernel(const float4* __restrict__ x, float4* __restrict__ out, int n4,
            const unsigned* __restrict__ state)
{
    float thr = __uint_as_float(state[7]);
    int idx = blockIdx.x * blockDim.x + threadIdx.x;
    int stride = gridDim.x * blockDim.x;
    for (int i = idx; i < n4; i += stride) {
        float4 v = x[i];
        float4 o;
        o.x = (v.x >= thr) ? 1.0f : 0.0f;
        o.y = (v.y >= thr) ? 1.0f : 0.0f;
        o.z = (v.z >= thr) ? 1.0f : 0.0f;
        o.w = (v.w >= thr) ? 1.0f : 0.0f;
        out[i] = o;
    }
}

// ---------------- host ----------------

extern "C" void kernel_launch(void* const* d_in, const int* in_sizes, int n_in,
                              void* d_out, int out_size, void* d_ws, size_t ws_size,
                              hipStream_t stream)
{
    const float* x = (const float*)d_in[0];
    float* out = (float*)d_out;
    long long n = (long long)in_sizes[0];
    long long k = (long long)((double)n * 0.9);   // matches Python int(n * RATIO)

    if (k <= 0) {
        hipMemsetAsync(d_out, 0, (size_t)out_size * sizeof(float), stream);
        return;
    }

    unsigned* ws = (unsigned*)d_ws;
    unsigned* st = ws + ST_OFF;
    int n4 = (int)(n / 4);
    const uint4* x4 = (const uint4*)x;
    unsigned r = (unsigned)(n - k);               // ascending rank of threshold

    size_t need_fast = (size_t)(CAND_OFF) * 4 + (size_t)NWAVES * SEG * 8;

    if (ws_size >= need_fast) {
        unsigned* h1   = ws + H1_OFF;
        unsigned* part = ws + PART_OFF;
        unsigned* h20  = ws + H20_OFF;
        unsigned* cntw = ws + CNT_OFF;
        uint2*    cand = (uint2*)(ws + CAND_OFF);

        hipMemsetAsync(d_ws, 0, (size_t)FIXED_Z * sizeof(unsigned), stream);

        hist12<<<2048, 256, 0, stream>>>(x4, n4, h1);
        scan_select<<<1, 1024, 0, stream>>>(h1, 4096, nullptr, 0, nullptr, r, &st[0], &st[1]);
        pass2<<<2048, 256, 0, stream>>>(x4, n4, (float4*)out, h20, cand, cntw, st);
        reduce_chunks<<<1024, 256, 0, stream>>>(h20, part);
        scan20<<<1, 1024, 0, stream>>>(h20, part, st);
        fixup<<<2048, 256, 0, stream>>>(cand, cntw, st, out, NWAVES);
    } else {
        unsigned* h1 = ws + FB_H1_OFF;
        unsigned* h2 = ws + FB_H2_OFF;
        unsigned* h3 = ws + FB_H3_OFF;

        hipMemsetAsync(d_ws, 0, FB_WS_INTS * sizeof(unsigned), stream);

        hist_pass<<<2048, 256, 0, stream>>>(x4, n4, 20, 4096, 0, st, h1);
        scan_select<<<1, 1024, 0, stream>>>(h1, 4096, nullptr, 0, nullptr, r, &st[0], &st[1]);
        hist_pass<<<2048, 256, 0, stream>>>(x4, n4, 8, 4096, 1, st, h2);
        scan_select<<<1, 1024, 0, stream>>>(h2, 4096, nullptr, 0, &st[1], 0u, &st[2], &st[3]);
        hist_pass<<<2048, 256, 0, stream>>>(x4, n4, 0, 256, 2, st, h3);
        scan_select<<<1, 1024, 0, stream>>>(h3, 256, nullptr, 0, &st[3], 0u, &st[4], &st[5]);
        finalize_thr_fb<<<1, 1, 0, stream>>>(st);
        mask_kernel<<<2048, 256, 0, stream>>>((const float4*)x, (float4*)out, n4, st);
    }
}